// Round 1
// baseline (99.843 us; speedup 1.0000x reference)
//
#include <hip/hip_runtime.h>
#include <math.h>

#define KMAX   64
#define HSIZE  256
#define EMPTY  0xFFFFFFFFu
#define SENT   0xFFFFFFFFu
#define LAM    300.0f

struct BWS {
    unsigned int hash[HSIZE];
    unsigned int uniq[KMAX];
    int nuniq;
    int ct;
    unsigned int counts[KMAX];
    float sum_p0[KMAX];
    float sum_p1[KMAX];
    float sum_p2[KMAX];
    float sum_t[KMAX];      // sum over pixels of (r+g+b), exact integers
    float mean0[KMAX];
    float mean1[KMAX];
    float mean2[KMAX];
    float m2[KMAX];
    float w_h[KMAX];        // counted ? 1/(3n) : 0
    float a_k[KMAX];        // active ? (10/sqrt(n))/n_out : 0
    unsigned int is_bg[KMAX];
    unsigned int counted[KMAX];
    float hs_sum;           // huber_loss + sep_loss accumulator
};

__device__ __forceinline__ unsigned key_of(float t0, float t1, float t2) {
    // colors are exact small integers in fp32
    return ((unsigned)t0 << 16) | ((unsigned)t1 << 8) | (unsigned)t2;
}

__global__ void k_init(BWS* ws, float* out) {
    int b = blockIdx.x;
    BWS* w = ws + b;
    int t = threadIdx.x;
    if (t < HSIZE) w->hash[t] = EMPTY;
    if (t < KMAX) {
        w->counts[t] = 0u;
        w->sum_p0[t] = 0.f; w->sum_p1[t] = 0.f; w->sum_p2[t] = 0.f;
        w->sum_t[t]  = 0.f;
    }
    if (t == 0) {
        w->hs_sum = 0.f;
        if (b == 0) out[0] = 0.f;
    }
}

// Build the set of unique color keys. Block-local shared hash dedup first,
// then ~#unique global CAS inserts per block.
__global__ void k_hash(const float* __restrict__ tgt, BWS* ws, int P) {
    int b = blockIdx.y;
    const float* t = tgt + (size_t)b * 3 * P;
    __shared__ unsigned sh[HSIZE];
    int tid = threadIdx.x;
    sh[tid] = EMPTY;                       // blockDim.x == 256 == HSIZE
    __syncthreads();

    int stride = gridDim.x * blockDim.x;
    for (int p = blockIdx.x * blockDim.x + tid; p < P; p += stride) {
        unsigned key = key_of(t[p], t[p + P], t[p + 2 * P]);
        unsigned slot = (key * 2654435761u) >> 24;
        for (int probe = 0; probe < HSIZE; ++probe) {
            unsigned old = atomicCAS(&sh[slot], EMPTY, key);
            if (old == EMPTY || old == key) break;
            slot = (slot + 1) & (HSIZE - 1);
        }
    }
    __syncthreads();

    unsigned key = sh[tid];
    if (key != EMPTY) {
        BWS* w = ws + b;
        unsigned slot = (key * 2654435761u) >> 24;
        for (int probe = 0; probe < HSIZE; ++probe) {
            unsigned old = atomicCAS(&w->hash[slot], EMPTY, key);
            if (old == EMPTY || old == key) break;
            slot = (slot + 1) & (HSIZE - 1);
        }
    }
}

// Compact hash table -> rank-sort (keys are distinct) -> sorted uniq[] padded
// with SENT (plays the role of BIG for the binary search).
__global__ void k_sort(BWS* ws) {
    int b = blockIdx.x;
    BWS* w = ws + b;
    __shared__ unsigned list[HSIZE];
    __shared__ int cnt;
    int t = threadIdx.x;
    if (t == 0) cnt = 0;
    if (t < KMAX) w->uniq[t] = SENT;
    __syncthreads();

    unsigned key = w->hash[t];
    int idx = -1;
    if (key != EMPTY) {
        idx = atomicAdd(&cnt, 1);
        list[idx] = key;
    }
    __syncthreads();
    int M = cnt;
    if (idx >= 0) {
        int rank = 0;
        for (int j = 0; j < M; ++j) rank += (list[j] < key) ? 1 : 0;
        if (rank < KMAX) w->uniq[rank] = key;
    }
    if (t == 0) w->nuniq = (M < KMAX) ? M : KMAX;
}

// Pass 1: per-pixel sid (binary search), segment counts & sums via shared
// accumulators, one global flush per block.
__global__ void k_pass1(const float* __restrict__ pred,
                        const float* __restrict__ tgt, BWS* ws, int P) {
    int b = blockIdx.y;
    BWS* w = ws + b;
    const float* tg = tgt + (size_t)b * 3 * P;
    const float* pr = pred + (size_t)b * 3 * P;

    __shared__ unsigned su[KMAX];
    __shared__ unsigned scnt[KMAX];
    __shared__ float sp0[KMAX], sp1[KMAX], sp2[KMAX], st[KMAX];
    int tid = threadIdx.x;
    if (tid < KMAX) {
        su[tid] = w->uniq[tid];
        scnt[tid] = 0u;
        sp0[tid] = 0.f; sp1[tid] = 0.f; sp2[tid] = 0.f; st[tid] = 0.f;
    }
    __syncthreads();

    int stride = gridDim.x * blockDim.x;
    for (int p = blockIdx.x * blockDim.x + tid; p < P; p += stride) {
        float t0 = tg[p], t1 = tg[p + P], t2 = tg[p + 2 * P];
        unsigned key = key_of(t0, t1, t2);
        int lo = 0, hi = KMAX;
        #pragma unroll
        for (int s = 0; s < 6; ++s) {
            int mid = (lo + hi) >> 1;
            if (su[mid] < key) lo = mid + 1; else hi = mid;
        }
        if (lo < KMAX) {
            atomicAdd(&scnt[lo], 1u);
            atomicAdd(&sp0[lo], pr[p]);
            atomicAdd(&sp1[lo], pr[p + P]);
            atomicAdd(&sp2[lo], pr[p + 2 * P]);
            atomicAdd(&st[lo],  t0 + t1 + t2);
        }
    }
    __syncthreads();
    if (tid < KMAX && scnt[tid] > 0) {
        atomicAdd(&w->counts[tid], scnt[tid]);
        atomicAdd(&w->sum_p0[tid], sp0[tid]);
        atomicAdd(&w->sum_p1[tid], sp1[tid]);
        atomicAdd(&w->sum_p2[tid], sp2[tid]);
        atomicAdd(&w->sum_t[tid],  st[tid]);
    }
}

// Derive per-segment quantities. One wave (64 threads) per batch.
__global__ void k_derive(BWS* ws, const unsigned char* __restrict__ no_bg, int P) {
    int b = blockIdx.x;
    BWS* w = ws + b;
    int k = threadIdx.x;   // blockDim.x == 64
    unsigned cnt = w->counts[k];
    bool valid = cnt > 0;
    float n = valid ? (float)cnt : 1.0f;
    float m0 = w->sum_p0[k] / n;
    float m1 = w->sum_p1[k] / n;
    float m2c = w->sum_p2[k] / n;
    float s = w->sum_t[k] / n;
    bool isbg = fabsf(s) < 1e-5f;
    bool nb = no_bg[b] != 0;
    bool counted = valid && (!isbg || !nb);
    int n_out_i = P - (int)cnt;
    bool active = valid && !isbg && (n_out_i > 0);
    float n_out = fmaxf((float)n_out_i, 1.0f);

    w->mean0[k] = m0; w->mean1[k] = m1; w->mean2[k] = m2c;
    w->m2[k] = m0 * m0 + m1 * m1 + m2c * m2c;
    w->w_h[k] = counted ? (1.0f / (3.0f * n)) : 0.0f;
    w->a_k[k] = active ? ((10.0f / sqrtf(n)) / n_out) : 0.0f;
    w->is_bg[k] = isbg ? 1u : 0u;
    w->counted[k] = counted ? 1u : 0u;

    unsigned long long mask = __ballot(counted);
    if (k == 0) w->ct = __popcll(mask);
}

// Pass 2: per-pixel huber + separation contributions, folded into one scalar.
__global__ void k_pass2(const float* __restrict__ pred,
                        const float* __restrict__ tgt, BWS* ws, int P) {
    int b = blockIdx.y;
    BWS* w = ws + b;
    const float* pr = pred + (size_t)b * 3 * P;
    const float* tg = tgt + (size_t)b * 3 * P;

    __shared__ unsigned su[KMAX];
    __shared__ float sm0[KMAX], sm1[KMAX], sm2[KMAX], sm2n[KMAX], swh[KMAX], sa[KMAX];
    __shared__ unsigned sbg[KMAX];
    __shared__ float wsum[8];
    int tid = threadIdx.x;
    if (tid < KMAX) {
        su[tid] = w->uniq[tid];
        sm0[tid] = w->mean0[tid];
        sm1[tid] = w->mean1[tid];
        sm2[tid] = w->mean2[tid];
        sm2n[tid] = w->m2[tid];
        swh[tid] = w->w_h[tid];
        sa[tid]  = w->a_k[tid];
        sbg[tid] = w->is_bg[tid];
    }
    __syncthreads();

    float acc = 0.f;
    int stride = gridDim.x * blockDim.x;
    for (int p = blockIdx.x * blockDim.x + tid; p < P; p += stride) {
        float p0 = pr[p], p1 = pr[p + P], p2 = pr[p + 2 * P];
        float t0 = tg[p], t1 = tg[p + P], t2 = tg[p + 2 * P];
        unsigned key = key_of(t0, t1, t2);
        int lo = 0, hi = KMAX;
        #pragma unroll
        for (int s = 0; s < 6; ++s) {
            int mid = (lo + hi) >> 1;
            if (su[mid] < key) lo = mid + 1; else hi = mid;
        }
        int sid = (lo < KMAX) ? lo : (KMAX - 1);

        float pf2 = p0 * p0 + p1 * p1 + p2 * p2;

        // huber vs (bg ? 0 : mean[sid])
        float r0 = sbg[sid] ? 0.f : sm0[sid];
        float r1 = sbg[sid] ? 0.f : sm1[sid];
        float r2 = sbg[sid] ? 0.f : sm2[sid];
        float e0 = p0 - r0, e1 = p1 - r1, e2 = p2 - r2;
        float a0 = fabsf(e0), a1 = fabsf(e1), a2 = fabsf(e2);
        float h = (a0 < 1.f ? 0.5f * e0 * e0 : a0 - 0.5f)
                + (a1 < 1.f ? 0.5f * e1 * e1 : a1 - 0.5f)
                + (a2 < 1.f ? 0.5f * e2 * e2 : a2 - 0.5f);
        float c = swh[sid] * h;

        float fsid = 0.f;
        #pragma unroll 16
        for (int k = 0; k < KMAX; ++k) {
            float d = pf2 + sm2n[k] - 2.0f * (p0 * sm0[k] + p1 * sm1[k] + p2 * sm2[k]);
            d = fmaxf(d, 0.0f);
            float f = LAM / (1.0f + d);
            c += sa[k] * f;
            if (k == sid) fsid = f;
        }
        c -= sa[sid] * fsid;    // "own" pixels excluded from sep mean
        acc += c;
    }

    // block reduction
    #pragma unroll
    for (int o = 32; o > 0; o >>= 1) acc += __shfl_xor(acc, o);
    int lane = tid & 63, wid = tid >> 6;
    if (lane == 0) wsum[wid] = acc;
    __syncthreads();
    if (tid == 0) {
        float tot = 0.f;
        int nw = blockDim.x >> 6;
        for (int i = 0; i < nw; ++i) tot += wsum[i];
        atomicAdd(&w->hs_sum, tot);
    }
}

// Final: K x K pairwise mean repulsion + combine. One wave per batch.
__global__ void k_final(BWS* ws, float* out, int B) {
    int tid = threadIdx.x;
    int b = tid >> 6, lane = tid & 63;
    BWS* w = ws + b;

    __shared__ float me0[2][KMAX], me1[2][KMAX], me2[2][KMAX];
    __shared__ unsigned cf[2][KMAX];

    bool isbg = w->is_bg[lane] != 0;
    bool cnted = w->counted[lane] != 0;
    float m0 = isbg ? 0.f : w->mean0[lane];
    float m1 = isbg ? 0.f : w->mean1[lane];
    float m2c = isbg ? 0.f : w->mean2[lane];
    me0[b][lane] = m0; me1[b][lane] = m1; me2[b][lane] = m2c;
    cf[b][lane] = cnted ? 1u : 0u;
    __syncthreads();

    float rs = 0.f;
    if (cnted) {
        for (int j = 0; j < KMAX; ++j) {
            if (j == lane || cf[b][j] == 0) continue;
            float d0 = m0 - me0[b][j];
            float d1 = m1 - me1[b][j];
            float d2 = m2c - me2[b][j];
            float sq = d0 * d0 + d1 * d1 + d2 * d2;
            rs += LAM / (sq + 1.0f);
        }
    }
    #pragma unroll
    for (int o = 32; o > 0; o >>= 1) rs += __shfl_xor(rs, o);

    if (lane == 0) {
        float pair_sum = rs * 0.5f;
        int ct = w->ct;
        float ctf = (float)ct;
        float npairs = ctf * (ctf - 1.0f) * 0.5f;
        float mean_sep = (ct > 1) ? (pair_sum / fmaxf(npairs, 1.0f)) : 0.0f;
        float loss = (w->hs_sum + mean_sep) / fmaxf(ctf, 1.0f);
        atomicAdd(out, loss / (float)B);
    }
}

extern "C" void kernel_launch(void* const* d_in, const int* in_sizes, int n_in,
                              void* d_out, int out_size, void* d_ws, size_t ws_size,
                              hipStream_t stream) {
    const float* pred = (const float*)d_in[0];
    const float* tgt  = (const float*)d_in[1];
    const unsigned char* nb = (const unsigned char*)d_in[2];
    float* out = (float*)d_out;

    int B = in_sizes[2];               // 2
    int P = in_sizes[0] / (3 * B);     // 512*512

    BWS* ws = (BWS*)d_ws;

    k_init  <<<B, 256, 0, stream>>>(ws, out);
    k_hash  <<<dim3(64, B), 256, 0, stream>>>(tgt, ws, P);
    k_sort  <<<B, 256, 0, stream>>>(ws);
    k_pass1 <<<dim3(64, B), 256, 0, stream>>>(pred, tgt, ws, P);
    k_derive<<<B, 64, 0, stream>>>(ws, nb, P);
    k_pass2 <<<dim3(256, B), 256, 0, stream>>>(pred, tgt, ws, P);
    k_final <<<1, 64 * B, 0, stream>>>(ws, out, B);
}